// Round 10
// baseline (1784.563 us; speedup 1.0000x reference)
//
#include <hip/hip_runtime.h>
#include <hip/hip_bf16.h>

// Problem constants (from reference)
#define Bb  32
#define Tt  12
#define Nn  5000
#define INc 2
#define Hh  128
#define HORc 12
#define Ee  80000
#define NTt (Bb*Nn)   // 160000

typedef float f4  __attribute__((ext_vector_type(4)));
typedef _Float16 h8 __attribute__((ext_vector_type(8)));
typedef _Float16 h4 __attribute__((ext_vector_type(4)));
typedef _Float16 h2 __attribute__((ext_vector_type(2)));

// block-shared LDS (halfs): actL[128][172] -- staged h, then hc, then r*hc; K-ext slots 128..159
#define HSTRIDE 172
#define BLK_LDS (128*HSTRIDE)   // 22016 halfs = 44032 B per block

__device__ __forceinline__ float ldf(const void* p, size_t i, int isbf){
  return isbf ? __bfloat162float(((const __hip_bfloat16*)p)[i]) : ((const float*)p)[i];
}
__device__ __forceinline__ int eidx(const int* e, int i, int is64){
  return is64 ? e[2*i] : e[i];
}
// sigmoid/tanh via hardware exp+rcp (saturation correct at +/-inf, no clamps)
__device__ __forceinline__ float sigm1(float x){
  return __builtin_amdgcn_rcpf(1.f + __expf(-x));
}
__device__ __forceinline__ float tanh1(float x){
  return 1.f - 2.f*__builtin_amdgcn_rcpf(1.f + __expf(2.f*x));
}

// ---------------- dtype detection ----------------
__global__ __launch_bounds__(256) void k_detect(const void* W2raw, const int* edge32, int* flags){
  __shared__ int cnt_bf, cnt_odd;
  if (threadIdx.x==0){ cnt_bf=0; cnt_odd=0; }
  __syncthreads();
  {
    unsigned w = ((const unsigned*)W2raw)[threadIdx.x];
    unsigned hb = (w>>8)&0x7Fu;
    if (hb>=0x34u && hb<=0x3Fu) atomicAdd(&cnt_bf,1);
  }
  if (threadIdx.x < 128){
    if (edge32[2*threadIdx.x+1] != 0) atomicAdd(&cnt_odd,1);
  }
  __syncthreads();
  if (threadIdx.x==0){
    flags[0] = (cnt_bf >= 128) ? 1 : 0;
    flags[1] = (cnt_odd == 0) ? 1 : 0;
  }
}

// ---------------- graph precompute ----------------
__global__ __launch_bounds__(256) void k_deg_cnt(const int* __restrict__ edge, int* deg, int* cnt,
                                                 const int* __restrict__ flags){
  int id = blockIdx.x*256 + threadIdx.x;
  int is64 = flags[1];
  if (id < Ee){
    atomicAdd(&deg[eidx(edge, id, is64)], 1);
    atomicAdd(&cnt[eidx(edge, Ee+id, is64)], 1);
  }
}

__global__ __launch_bounds__(256) void k_dis(const int* __restrict__ deg, float* dis){
  int id = blockIdx.x*256 + threadIdx.x;
  if (id < Nn){
    int d = deg[id];
    dis[id] = d > 0 ? rsqrtf((float)d) : 0.f;
  }
}

__global__ __launch_bounds__(1024) void k_scan(const int* __restrict__ cnt, int* rowptr){
  __shared__ int part[1024];
  int t = threadIdx.x;
  int base = t*5;
  int s = 0;
  #pragma unroll
  for (int j=0;j<5;j++){ int idx=base+j; if (idx<Nn) s += cnt[idx]; }
  part[t] = s; __syncthreads();
  for (int off=1; off<1024; off<<=1){
    int add = (t>=off) ? part[t-off] : 0;
    __syncthreads();
    part[t] += add;
    __syncthreads();
  }
  int run = (t>0) ? part[t-1] : 0;
  #pragma unroll
  for (int j=0;j<5;j++){
    int idx = base+j;
    if (idx < Nn){ rowptr[idx] = run; run += cnt[idx]; }
  }
  if (t == 1023) rowptr[Nn] = part[1023];
}

__global__ __launch_bounds__(256) void k_fill(const int* __restrict__ edge,
                                              const int* __restrict__ rowptr,
                                              int* fillc, int* csr,
                                              const int* __restrict__ flags){
  int id = blockIdx.x*256 + threadIdx.x;
  int is64 = flags[1];
  if (id < Ee){
    int d = eidx(edge, Ee+id, is64);
    int pos = atomicAdd(&fillc[d], 1);
    csr[rowptr[d] + pos] = eidx(edge, id, is64);
  }
}

// ---------------- weight precompute (element-parallel) ----------------
__global__ __launch_bounds__(128) void k_wx(
  const void* __restrict__ W1, const void* __restrict__ b1,
  const void* __restrict__ W2, const void* __restrict__ b2,
  const void* __restrict__ Wz, const void* __restrict__ bz,
  const void* __restrict__ Wr, const void* __restrict__ br,
  const void* __restrict__ Wc, const void* __restrict__ bc,
  _Float16* __restrict__ Wext, _Float16* __restrict__ Whc,
  const int* __restrict__ flags)
{
  int bid = blockIdx.x, f = threadIdx.x;
  int isbf = flags[0];
  if (bid < 640){
    int s = bid/160, k = bid - s*160;
    float v = 0.f;
    if (k < 128){
      if (s == 0)
        v = ldf(W2,(size_t)k*128+f,isbf) - ldf(W2,(size_t)(2*128+k)*128+f,isbf);
      else {
        const void* Wg = (s==1)?Wz:((s==2)?Wr:Wc);
        v = ldf(Wg,(size_t)(128+k)*128+f,isbf);
      }
    } else if (s == 0){
      v = (k==128) ? ldf(b2,f,isbf) : 0.f;
    } else if (k < 134){
      const void* Wg = (s==1)?Wz:((s==2)?Wr:Wc);
      int q = k - 128;
      float acc = 0.f;
      for (int j=0;j<128;j++) acc += ldf(W1,(size_t)q*128+j,isbf)*ldf(Wg,(size_t)j*128+f,isbf);
      v = acc;
    } else if (k == 134){
      const void* Wg = (s==1)?Wz:((s==2)?Wr:Wc);
      const void* bg = (s==1)?bz:((s==2)?br:bc);
      float acc = ldf(bg,f,isbf);
      for (int j=0;j<128;j++) acc += ldf(b1,j,isbf)*ldf(Wg,(size_t)j*128+f,isbf);
      v = acc;
    }
    Wext[(size_t)(s*128+f)*160 + k] = (_Float16)v;
  } else {
    int k = bid - 640;  // 0..255
    float v = (k < 128) ? ldf(W2,(size_t)(128+k)*128+f,isbf)
                        : 2.f*ldf(W2,(size_t)(2*128+(k-128))*128+f,isbf);
    Whc[(size_t)f*256 + k] = (_Float16)v;
  }
}

// ---------------- x propagation (all timesteps at once) ----------------
__global__ __launch_bounds__(256) void k_px1(
  const void* __restrict__ x, const float* __restrict__ dis,
  const int* __restrict__ rowptr, const int* __restrict__ csr, float* __restrict__ px1,
  const int* __restrict__ flags)
{
  int id = blockIdx.x*256 + threadIdx.x;
  int isbf = flags[0];
  if (id < Tt*Nn){
    int t = id / Nn, n = id - t*Nn;
    int e0 = rowptr[n], e1 = rowptr[n+1];
    float a0=0.f, a1=0.f;
    for (int e=e0;e<e1;e++){
      int s = csr[e]; float ds = dis[s];
      size_t xb = (size_t)(t*Nn+s)*2;
      a0 += ds*ldf(x,xb+0,isbf); a1 += ds*ldf(x,xb+1,isbf);
    }
    float dn = -dis[n];
    px1[id*2+0] = dn*a0; px1[id*2+1] = dn*a1;
  }
}

__global__ __launch_bounds__(256) void k_px2(
  const float* __restrict__ px1, const float* __restrict__ dis,
  const int* __restrict__ rowptr, const int* __restrict__ csr, float* __restrict__ px2)
{
  int id = blockIdx.x*256 + threadIdx.x;
  if (id < Tt*Nn){
    int t = id / Nn, n = id - t*Nn;
    int e0 = rowptr[n], e1 = rowptr[n+1];
    float a0=0.f, a1=0.f;
    for (int e=e0;e<e1;e++){
      int s = csr[e]; float ds = dis[s];
      const float* pp = px1 + (size_t)(t*Nn+s)*2;
      a0 += ds*pp[0]; a1 += ds*pp[1];
    }
    float dn = -dis[n];
    px2[id*2+0] = dn*a0; px2[id*2+1] = dn*a1;
  }
}

// ---------------- per-step h propagation (fp16, 4 nodes/block) ----------------
__global__ __launch_bounds__(256) void k_ph1(
  const _Float16* __restrict__ h16, const float* __restrict__ dis,
  const int* __restrict__ rowptr, const int* __restrict__ csr,
  _Float16* __restrict__ phh)
{
  int n = blockIdx.x*4 + (threadIdx.x>>6);
  int f2 = threadIdx.x & 63;
  int e0 = rowptr[n], e1 = rowptr[n+1];
  float a0=0.f, a1=0.f;
  for (int e=e0;e<e1;e++){
    int s = csr[e]; float ds = dis[s];
    h2 v = *(const h2*)(h16 + (size_t)s*128 + 2*f2);
    a0 += ds*(float)v[0]; a1 += ds*(float)v[1];
  }
  float dn = -dis[n];
  h2 o; o[0]=(_Float16)(dn*a0); o[1]=(_Float16)(dn*a1);
  *(h2*)(phh + (size_t)n*256 + 2*f2) = o;
}

__global__ __launch_bounds__(256) void k_ph2(
  const float* __restrict__ dis,
  const int* __restrict__ rowptr, const int* __restrict__ csr,
  _Float16* __restrict__ phh)
{
  int n = blockIdx.x*4 + (threadIdx.x>>6);
  int f2 = threadIdx.x & 63;
  int e0 = rowptr[n], e1 = rowptr[n+1];
  float a0=0.f, a1=0.f;
  for (int e=e0;e<e1;e++){
    int s = csr[e]; float ds = dis[s];
    h2 v = *(const h2*)(phh + (size_t)s*256 + 2*f2);
    a0 += ds*(float)v[0]; a1 += ds*(float)v[1];
  }
  float dn = -dis[n];
  h2 o; o[0]=(_Float16)(dn*a0); o[1]=(_Float16)(dn*a1);
  *(h2*)(phh + (size_t)n*256 + 128 + 2*f2) = o;
}

// ---------------- fused GRU step, MFMA (feature-split decomposition) ----------------
// Block = 128 nodes; wave w owns features [w*32, w*32+32) x all 128 nodes.
// A (weights) read once per block per stage; B (activations) from block-shared actL.
// out^T: C[f][n]; C-frag: f = w*32 + ft*16 + g*4 + r, n = nt*16 + n16.

template<int S>
__device__ __forceinline__ void stage_mm(
  const _Float16* __restrict__ Wst, const _Float16* __restrict__ Whc,
  const _Float16* __restrict__ phh, _Float16* __restrict__ actL,
  h4 (&zr)[16], _Float16* __restrict__ h16,
  int nb, int w, int lane, bool graphblk)
{
  int n16 = lane & 15, g = lane >> 4, q8 = g*8;
  h8 zz = {0,0,0,0,0,0,0,0};
  f4 z4 = {0.f,0.f,0.f,0.f};
  f4 acc[2][8];
  #pragma unroll
  for (int ft=0;ft<2;ft++)
    #pragma unroll
    for (int nt=0;nt<8;nt++) acc[ft][nt] = z4;

  // A-frags for both f-tiles stay live across the nt loop (read once per block-stage)
  h8 A[2][5];
  #pragma unroll
  for (int ft=0;ft<2;ft++){
    const _Float16* Wa = Wst + (size_t)(w*32 + ft*16 + n16)*160 + q8;
    #pragma unroll
    for (int ks=0;ks<5;ks++) A[ft][ks] = *(const h8*)(Wa + ks*32);
  }
  #pragma unroll
  for (int nt=0; nt<8; nt++){
    const _Float16* br = &actL[(nt*16+n16)*HSTRIDE + q8];
    h8 b[5];
    b[0] = *(const h8*)(br);
    b[1] = *(const h8*)(br + 32);
    b[2] = *(const h8*)(br + 64);
    b[3] = *(const h8*)(br + 96);
    if (S == 0){ h8 e = zz; if (g==0) e[0] = (_Float16)1.f; b[4] = e; }  // bias slot k=128
    else b[4] = *(const h8*)(br + 128);                                   // x/u/1 slots
    #pragma unroll
    for (int ks=0;ks<5;ks++){
      acc[0][nt] = __builtin_amdgcn_mfma_f32_16x16x32_f16(A[0][ks], b[ks], acc[0][nt], 0,0,0);
      acc[1][nt] = __builtin_amdgcn_mfma_f32_16x16x32_f16(A[1][ks], b[ks], acc[1][nt], 0,0,0);
    }
  }
  // graph correction (stage 0, blocks with nodes < Nn): K-extended by 256 via Whc x phh
  if (S == 0 && graphblk){
    #pragma unroll
    for (int ft=0;ft<2;ft++){
      const _Float16* Wb = Whc + (size_t)(w*32 + ft*16 + n16)*256 + q8;
      h8 A2[8];
      #pragma unroll
      for (int ks=0;ks<8;ks++) A2[ks] = *(const h8*)(Wb + ks*32);
      #pragma unroll
      for (int nt=0; nt<8; nt++){
        int node = nb + nt*16 + n16;
        bool ok = node < Nn;
        const _Float16* pp = phh + (size_t)(ok ? node : 0)*256 + q8;
        #pragma unroll
        for (int ks=0;ks<8;ks++){
          h8 bb = *(const h8*)(pp + ks*32);
          if (!ok) bb = zz;
          acc[ft][nt] = __builtin_amdgcn_mfma_f32_16x16x32_f16(A2[ks], bb, acc[ft][nt], 0,0,0);
        }
      }
    }
  }
  // stages that overwrite actL: wait for all waves' reads before writing
  if (S == 0 || S == 2) __syncthreads();
  #pragma unroll
  for (int ft=0;ft<2;ft++)
    #pragma unroll
    for (int nt=0;nt<8;nt++){
      int fb = w*32 + ft*16 + g*4;       // 4 consecutive features
      int nrow = nt*16 + n16;
      f4 a = acc[ft][nt];
      if (S == 0){
        h4 o;
        #pragma unroll
        for (int r=0;r<4;r++) o[r] = (_Float16)a[r];
        *(h4*)&actL[nrow*HSTRIDE + fb] = o;
      } else if (S == 1){
        h4 o;
        #pragma unroll
        for (int r=0;r<4;r++) o[r] = (_Float16)sigm1(a[r]);
        zr[ft*8+nt] = o;                  // z stays in registers (same wave owns frag in S3)
      } else if (S == 2){
        h4 hcv = *(const h4*)&actL[nrow*HSTRIDE + fb];
        h4 o;
        #pragma unroll
        for (int r=0;r<4;r++) o[r] = (_Float16)(sigm1(a[r]) * (float)hcv[r]);
        *(h4*)&actL[nrow*HSTRIDE + fb] = o;
      } else {
        h4 ho = *(const h4*)(h16 + (size_t)(nb+nrow)*128 + fb);
        h4 zv = zr[ft*8+nt];
        h4 o;
        #pragma unroll
        for (int r=0;r<4;r++){
          float z = (float)zv[r];
          o[r] = (_Float16)(z*(float)ho[r] + (1.f - z)*tanh1(a[r]));
        }
        *(h4*)(h16 + (size_t)(nb+nrow)*128 + fb) = o;
      }
    }
  if (S == 0 || S == 2) __syncthreads();
}

__global__ __launch_bounds__(256, 2) void k_mainm(
    _Float16* __restrict__ h16, const void* __restrict__ x,
    const float* __restrict__ px1, const float* __restrict__ px2,
    const _Float16* __restrict__ phh,
    const _Float16* __restrict__ Wext, const _Float16* __restrict__ Whc,
    const int* __restrict__ flags, int t)
{
  __shared__ _Float16 actL[BLK_LDS];   // 44032 B
  int tid = threadIdx.x;
  int w = tid >> 6, lane = tid & 63;
  int nb = blockIdx.x*128;

  // ---- stage h16 -> actL[n][0..127]
  {
    int row = tid >> 1, c0 = (tid & 1)*64;
    const _Float16* hp = h16 + (size_t)(nb+row)*128 + c0;
    _Float16* dst = actL + row*HSTRIDE + c0;
    #pragma unroll
    for (int j=0;j<8;j++){
      h8 v = *(const h8*)(hp + j*8);
      h4* pv = (h4*)&v;
      *(h4*)(dst + j*8)     = pv[0];
      *(h4*)(dst + j*8 + 4) = pv[1];
    }
  }
  // ---- K-extension slots: actL[n][128..134] = {x0,x1,u1a,u1b,u2a,u2b,1}, 135..159 = 0
  if (tid < 128){
    int n = tid;
    _Float16* row = actL + n*HSTRIDE;
    for (int k=135;k<160;k++) row[k] = (_Float16)0.f;
    int isbf = flags[0];
    int i = nb + n;
    int b = i / Nn, nn2 = i - b*Nn;
    size_t xb = ((size_t)(b*Tt + t)*Nn + nn2)*2;
    float x0 = ldf(x,xb+0,isbf), x1 = ldf(x,xb+1,isbf);
    float u1a=0.f,u1b=0.f,u2a=-x0,u2b=-x1;   // nodes >= Nn: Tx1=0, Tx2=-x
    if (i < Nn){
      u1a = px1[(t*Nn+i)*2+0]; u1b = px1[(t*Nn+i)*2+1];
      u2a = 2.f*px2[(t*Nn+i)*2+0] - x0; u2b = 2.f*px2[(t*Nn+i)*2+1] - x1;
    }
    row[128]=(_Float16)x0;  row[129]=(_Float16)x1;
    row[130]=(_Float16)u1a; row[131]=(_Float16)u1b;
    row[132]=(_Float16)u2a; row[133]=(_Float16)u2b;
    row[134]=(_Float16)1.f;
  }
  __syncthreads();

  bool graphblk = (nb < Nn);   // block-uniform
  h4 zr[16];
  stage_mm<0>(Wext + 0*20480, Whc, phh, actL, zr, h16, nb, w, lane, graphblk);
  stage_mm<1>(Wext + 1*20480, Whc, phh, actL, zr, h16, nb, w, lane, graphblk);
  stage_mm<2>(Wext + 2*20480, Whc, phh, actL, zr, h16, nb, w, lane, graphblk);
  stage_mm<3>(Wext + 3*20480, Whc, phh, actL, zr, h16, nb, w, lane, graphblk);
}

// ---------------- output projection ----------------
__global__ __launch_bounds__(256) void k_out(
  const _Float16* __restrict__ h16, const void* __restrict__ Wo,
  const void* __restrict__ bo, void* __restrict__ out,
  const int* __restrict__ flags)
{
  __shared__ float wol[128*HORc];
  __shared__ float wob[HORc];
  int isbf = flags[0];
  for (int idx=threadIdx.x; idx<128*HORc; idx+=256) wol[idx] = ldf(Wo, idx, isbf);
  if (threadIdx.x < HORc) wob[threadIdx.x] = ldf(bo, threadIdx.x, isbf);
  __syncthreads();

  int i = blockIdx.x*256 + threadIdx.x;
  if (i < NTt){
    float acc[HORc];
    #pragma unroll
    for (int j=0;j<HORc;j++) acc[j] = wob[j];
    const _Float16* hp = h16 + (size_t)i*128;
    for (int kb=0;kb<16;kb++){
      h8 hv = *(const h8*)(hp + kb*8);
      #pragma unroll
      for (int j=0;j<8;j++){
        float hvf = (float)hv[j];
        #pragma unroll
        for (int jj=0;jj<HORc;jj++) acc[jj] += hvf * wol[(kb*8+j)*HORc + jj];
      }
    }
    int b = i / Nn, n = i - b*Nn;
    #pragma unroll
    for (int j=0;j<HORc;j++){
      size_t oi = (size_t)(b*HORc+j)*Nn + n;
      if (isbf) ((__hip_bfloat16*)out)[oi] = __float2bfloat16(acc[j]);
      else      ((float*)out)[oi] = acc[j];
    }
  }
}

// ---------------- host ----------------
extern "C" void kernel_launch(void* const* d_in, const int* in_sizes, int n_in,
                              void* d_out, int out_size, void* d_ws, size_t ws_size,
                              hipStream_t stream) {
  (void)in_sizes; (void)n_in; (void)out_size; (void)ws_size;
  const void* x   = d_in[0];
  const int*  edge= (const int*)d_in[1];
  const void* W1  = d_in[2];
  const void* b1  = d_in[3];
  const void* W2  = d_in[4];
  const void* b2  = d_in[5];
  const void* Wz  = d_in[6];
  const void* bz  = d_in[7];
  const void* Wr  = d_in[8];
  const void* br  = d_in[9];
  const void* Wc  = d_in[10];
  const void* bc  = d_in[11];
  const void* Wo  = d_in[12];
  const void* bo  = d_in[13];

  char* ws = (char*)d_ws;
  size_t off = 0;
  auto alloc = [&](size_t bytes)->char*{
    char* p = ws + off;
    off += (bytes + 255) & ~(size_t)255;
    return p;
  };
  _Float16* h16  = (_Float16*)alloc((size_t)NTt*128*2);   // 41 MB, zeroed
  int*   deg   = (int*)  alloc(Nn*4);                     // zeroed
  int*   cnt   = (int*)  alloc(Nn*4);                     // zeroed
  int*   fillc = (int*)  alloc(Nn*4);                     // zeroed
  size_t zlen = off;
  int*   flags = (int*)  alloc(16*4);
  float* dis   = (float*)alloc(Nn*4);
  int*   rowptr= (int*)  alloc((Nn+1)*4);
  int*   csr   = (int*)  alloc(Ee*4);
  float* px1   = (float*)alloc((size_t)Tt*Nn*2*4);
  float* px2   = (float*)alloc((size_t)Tt*Nn*2*4);
  _Float16* phh  = (_Float16*)alloc((size_t)5120*256*2);  // ph1|ph2 fp16 rows (padded)
  _Float16* Wext = (_Float16*)alloc((size_t)4*128*160*2);
  _Float16* Whc  = (_Float16*)alloc((size_t)128*256*2);

  hipMemsetAsync(d_ws, 0, zlen, stream);

  k_detect <<<1,256,0,stream>>>(W2, edge, flags);
  k_deg_cnt<<<(Ee+255)/256,256,0,stream>>>(edge, deg, cnt, flags);
  k_dis    <<<(Nn+255)/256,256,0,stream>>>(deg, dis);
  k_scan   <<<1,1024,0,stream>>>(cnt, rowptr);
  k_fill   <<<(Ee+255)/256,256,0,stream>>>(edge, rowptr, fillc, csr, flags);
  k_wx     <<<896,128,0,stream>>>(W1,b1,W2,b2,Wz,bz,Wr,br,Wc,bc, Wext, Whc, flags);
  k_px1    <<<(Tt*Nn+255)/256,256,0,stream>>>(x, dis, rowptr, csr, px1, flags);
  k_px2    <<<(Tt*Nn+255)/256,256,0,stream>>>(px1, dis, rowptr, csr, px2);

  for (int t=0; t<Tt; ++t){
    k_ph1  <<<Nn/4,256,0,stream>>>(h16, dis, rowptr, csr, phh);
    k_ph2  <<<Nn/4,256,0,stream>>>(dis, rowptr, csr, phh);
    k_mainm<<<NTt/128,256,0,stream>>>(h16, x, px1, px2, phh, Wext, Whc, flags, t);
  }

  k_out<<<(NTt+255)/256,256,0,stream>>>(h16, Wo, bo, d_out, flags);
}

// Round 11
// 1731.269 us; speedup vs baseline: 1.0308x; 1.0308x over previous
//
#include <hip/hip_runtime.h>
#include <hip/hip_bf16.h>

// Problem constants (from reference)
#define Bb  32
#define Tt  12
#define Nn  5000
#define INc 2
#define Hh  128
#define HORc 12
#define Ee  80000
#define NTt (Bb*Nn)   // 160000

typedef float f4  __attribute__((ext_vector_type(4)));
typedef _Float16 h8 __attribute__((ext_vector_type(8)));
typedef _Float16 h4 __attribute__((ext_vector_type(4)));
typedef _Float16 h2 __attribute__((ext_vector_type(2)));

// block-shared LDS (halfs): actL[128][172] -- staged h, then hc, then r*hc; K-ext slots 128..159
#define HSTRIDE 172
#define BLK_LDS (128*HSTRIDE)   // 22016 halfs = 44032 B per block

__device__ __forceinline__ float ldf(const void* p, size_t i, int isbf){
  return isbf ? __bfloat162float(((const __hip_bfloat16*)p)[i]) : ((const float*)p)[i];
}
__device__ __forceinline__ int eidx(const int* e, int i, int is64){
  return is64 ? e[2*i] : e[i];
}
// sigmoid/tanh via hardware exp+rcp (saturation correct at +/-inf, no clamps)
__device__ __forceinline__ float sigm1(float x){
  return __builtin_amdgcn_rcpf(1.f + __expf(-x));
}
__device__ __forceinline__ float tanh1(float x){
  return 1.f - 2.f*__builtin_amdgcn_rcpf(1.f + __expf(2.f*x));
}

// ---------------- dtype detection ----------------
__global__ __launch_bounds__(256) void k_detect(const void* W2raw, const int* edge32, int* flags){
  __shared__ int cnt_bf, cnt_odd;
  if (threadIdx.x==0){ cnt_bf=0; cnt_odd=0; }
  __syncthreads();
  {
    unsigned w = ((const unsigned*)W2raw)[threadIdx.x];
    unsigned hb = (w>>8)&0x7Fu;
    if (hb>=0x34u && hb<=0x3Fu) atomicAdd(&cnt_bf,1);
  }
  if (threadIdx.x < 128){
    if (edge32[2*threadIdx.x+1] != 0) atomicAdd(&cnt_odd,1);
  }
  __syncthreads();
  if (threadIdx.x==0){
    flags[0] = (cnt_bf >= 128) ? 1 : 0;
    flags[1] = (cnt_odd == 0) ? 1 : 0;
  }
}

// ---------------- graph precompute ----------------
__global__ __launch_bounds__(256) void k_deg_cnt(const int* __restrict__ edge, int* deg, int* cnt,
                                                 const int* __restrict__ flags){
  int id = blockIdx.x*256 + threadIdx.x;
  int is64 = flags[1];
  if (id < Ee){
    atomicAdd(&deg[eidx(edge, id, is64)], 1);
    atomicAdd(&cnt[eidx(edge, Ee+id, is64)], 1);
  }
}

__global__ __launch_bounds__(256) void k_dis(const int* __restrict__ deg, float* dis){
  int id = blockIdx.x*256 + threadIdx.x;
  if (id < Nn){
    int d = deg[id];
    dis[id] = d > 0 ? rsqrtf((float)d) : 0.f;
  }
}

__global__ __launch_bounds__(1024) void k_scan(const int* __restrict__ cnt, int* rowptr){
  __shared__ int part[1024];
  int t = threadIdx.x;
  int base = t*5;
  int s = 0;
  #pragma unroll
  for (int j=0;j<5;j++){ int idx=base+j; if (idx<Nn) s += cnt[idx]; }
  part[t] = s; __syncthreads();
  for (int off=1; off<1024; off<<=1){
    int add = (t>=off) ? part[t-off] : 0;
    __syncthreads();
    part[t] += add;
    __syncthreads();
  }
  int run = (t>0) ? part[t-1] : 0;
  #pragma unroll
  for (int j=0;j<5;j++){
    int idx = base+j;
    if (idx < Nn){ rowptr[idx] = run; run += cnt[idx]; }
  }
  if (t == 1023) rowptr[Nn] = part[1023];
}

__global__ __launch_bounds__(256) void k_fill(const int* __restrict__ edge,
                                              const int* __restrict__ rowptr,
                                              int* fillc, int* csr,
                                              const int* __restrict__ flags){
  int id = blockIdx.x*256 + threadIdx.x;
  int is64 = flags[1];
  if (id < Ee){
    int d = eidx(edge, Ee+id, is64);
    int pos = atomicAdd(&fillc[d], 1);
    csr[rowptr[d] + pos] = eidx(edge, id, is64);
  }
}

// ---------------- weight precompute (element-parallel) ----------------
__global__ __launch_bounds__(128) void k_wx(
  const void* __restrict__ W1, const void* __restrict__ b1,
  const void* __restrict__ W2, const void* __restrict__ b2,
  const void* __restrict__ Wz, const void* __restrict__ bz,
  const void* __restrict__ Wr, const void* __restrict__ br,
  const void* __restrict__ Wc, const void* __restrict__ bc,
  _Float16* __restrict__ Wext, _Float16* __restrict__ Whc,
  const int* __restrict__ flags)
{
  int bid = blockIdx.x, f = threadIdx.x;
  int isbf = flags[0];
  if (bid < 640){
    int s = bid/160, k = bid - s*160;
    float v = 0.f;
    if (k < 128){
      if (s == 0)
        v = ldf(W2,(size_t)k*128+f,isbf) - ldf(W2,(size_t)(2*128+k)*128+f,isbf);
      else {
        const void* Wg = (s==1)?Wz:((s==2)?Wr:Wc);
        v = ldf(Wg,(size_t)(128+k)*128+f,isbf);
      }
    } else if (s == 0){
      v = (k==128) ? ldf(b2,f,isbf) : 0.f;
    } else if (k < 134){
      const void* Wg = (s==1)?Wz:((s==2)?Wr:Wc);
      int q = k - 128;
      float acc = 0.f;
      for (int j=0;j<128;j++) acc += ldf(W1,(size_t)q*128+j,isbf)*ldf(Wg,(size_t)j*128+f,isbf);
      v = acc;
    } else if (k == 134){
      const void* Wg = (s==1)?Wz:((s==2)?Wr:Wc);
      const void* bg = (s==1)?bz:((s==2)?br:bc);
      float acc = ldf(bg,f,isbf);
      for (int j=0;j<128;j++) acc += ldf(b1,j,isbf)*ldf(Wg,(size_t)j*128+f,isbf);
      v = acc;
    }
    Wext[(size_t)(s*128+f)*160 + k] = (_Float16)v;
  } else {
    int k = bid - 640;  // 0..255
    float v = (k < 128) ? ldf(W2,(size_t)(128+k)*128+f,isbf)
                        : 2.f*ldf(W2,(size_t)(2*128+(k-128))*128+f,isbf);
    Whc[(size_t)f*256 + k] = (_Float16)v;
  }
}

// ---------------- x propagation (all timesteps at once) ----------------
__global__ __launch_bounds__(256) void k_px1(
  const void* __restrict__ x, const float* __restrict__ dis,
  const int* __restrict__ rowptr, const int* __restrict__ csr, float* __restrict__ px1,
  const int* __restrict__ flags)
{
  int id = blockIdx.x*256 + threadIdx.x;
  int isbf = flags[0];
  if (id < Tt*Nn){
    int t = id / Nn, n = id - t*Nn;
    int e0 = rowptr[n], e1 = rowptr[n+1];
    float a0=0.f, a1=0.f;
    for (int e=e0;e<e1;e++){
      int s = csr[e]; float ds = dis[s];
      size_t xb = (size_t)(t*Nn+s)*2;
      a0 += ds*ldf(x,xb+0,isbf); a1 += ds*ldf(x,xb+1,isbf);
    }
    float dn = -dis[n];
    px1[id*2+0] = dn*a0; px1[id*2+1] = dn*a1;
  }
}

__global__ __launch_bounds__(256) void k_px2(
  const float* __restrict__ px1, const float* __restrict__ dis,
  const int* __restrict__ rowptr, const int* __restrict__ csr, float* __restrict__ px2)
{
  int id = blockIdx.x*256 + threadIdx.x;
  if (id < Tt*Nn){
    int t = id / Nn, n = id - t*Nn;
    int e0 = rowptr[n], e1 = rowptr[n+1];
    float a0=0.f, a1=0.f;
    for (int e=e0;e<e1;e++){
      int s = csr[e]; float ds = dis[s];
      const float* pp = px1 + (size_t)(t*Nn+s)*2;
      a0 += ds*pp[0]; a1 += ds*pp[1];
    }
    float dn = -dis[n];
    px2[id*2+0] = dn*a0; px2[id*2+1] = dn*a1;
  }
}

// ---------------- per-step h propagation (fp16, 4 nodes/block) ----------------
__global__ __launch_bounds__(256) void k_ph1(
  const _Float16* __restrict__ h16, const float* __restrict__ dis,
  const int* __restrict__ rowptr, const int* __restrict__ csr,
  _Float16* __restrict__ phh)
{
  int n = blockIdx.x*4 + (threadIdx.x>>6);
  int f2 = threadIdx.x & 63;
  int e0 = rowptr[n], e1 = rowptr[n+1];
  float a0=0.f, a1=0.f;
  for (int e=e0;e<e1;e++){
    int s = csr[e]; float ds = dis[s];
    h2 v = *(const h2*)(h16 + (size_t)s*128 + 2*f2);
    a0 += ds*(float)v[0]; a1 += ds*(float)v[1];
  }
  float dn = -dis[n];
  h2 o; o[0]=(_Float16)(dn*a0); o[1]=(_Float16)(dn*a1);
  *(h2*)(phh + (size_t)n*256 + 2*f2) = o;
}

__global__ __launch_bounds__(256) void k_ph2(
  const float* __restrict__ dis,
  const int* __restrict__ rowptr, const int* __restrict__ csr,
  _Float16* __restrict__ phh)
{
  int n = blockIdx.x*4 + (threadIdx.x>>6);
  int f2 = threadIdx.x & 63;
  int e0 = rowptr[n], e1 = rowptr[n+1];
  float a0=0.f, a1=0.f;
  for (int e=e0;e<e1;e++){
    int s = csr[e]; float ds = dis[s];
    h2 v = *(const h2*)(phh + (size_t)s*256 + 2*f2);
    a0 += ds*(float)v[0]; a1 += ds*(float)v[1];
  }
  float dn = -dis[n];
  h2 o; o[0]=(_Float16)(dn*a0); o[1]=(_Float16)(dn*a1);
  *(h2*)(phh + (size_t)n*256 + 128 + 2*f2) = o;
}

// ---------------- fused GRU step, MFMA (feature-split decomposition) ----------------
// Block = 128 nodes; wave w owns features [w*32, w*32+32) x all 128 nodes.
// A (weights) read once per block per stage; B (activations) from block-shared actL.
// out^T: C[f][n]; C-frag: f = w*32 + ft*16 + g*4 + r, n = nt*16 + n16.

template<int S>
__device__ __forceinline__ void stage_mm(
  const _Float16* __restrict__ Wst, const _Float16* __restrict__ Whc,
  const _Float16* __restrict__ phh, _Float16* __restrict__ actL,
  h4 (&zr)[16], _Float16* __restrict__ h16,
  int nb, int w, int lane, bool graphblk)
{
  int n16 = lane & 15, g = lane >> 4, q8 = g*8;
  h8 zz = {0,0,0,0,0,0,0,0};
  f4 z4 = {0.f,0.f,0.f,0.f};
  f4 acc[2][8];
  #pragma unroll
  for (int ft=0;ft<2;ft++)
    #pragma unroll
    for (int nt=0;nt<8;nt++) acc[ft][nt] = z4;

  // A-frags for both f-tiles stay live across the nt loop (read once per block-stage)
  h8 A[2][5];
  #pragma unroll
  for (int ft=0;ft<2;ft++){
    const _Float16* Wa = Wst + (size_t)(w*32 + ft*16 + n16)*160 + q8;
    #pragma unroll
    for (int ks=0;ks<5;ks++) A[ft][ks] = *(const h8*)(Wa + ks*32);
  }
  #pragma unroll
  for (int nt=0; nt<8; nt++){
    const _Float16* br = &actL[(nt*16+n16)*HSTRIDE + q8];
    h8 b[5];
    b[0] = *(const h8*)(br);
    b[1] = *(const h8*)(br + 32);
    b[2] = *(const h8*)(br + 64);
    b[3] = *(const h8*)(br + 96);
    if (S == 0){ h8 e = zz; if (g==0) e[0] = (_Float16)1.f; b[4] = e; }  // bias slot k=128
    else b[4] = *(const h8*)(br + 128);                                   // x/u/1 slots
    #pragma unroll
    for (int ks=0;ks<5;ks++){
      acc[0][nt] = __builtin_amdgcn_mfma_f32_16x16x32_f16(A[0][ks], b[ks], acc[0][nt], 0,0,0);
      acc[1][nt] = __builtin_amdgcn_mfma_f32_16x16x32_f16(A[1][ks], b[ks], acc[1][nt], 0,0,0);
    }
  }
  // graph correction (stage 0, blocks with nodes < Nn): K-extended by 256 via Whc x phh
  if (S == 0 && graphblk){
    #pragma unroll
    for (int ft=0;ft<2;ft++){
      const _Float16* Wb = Whc + (size_t)(w*32 + ft*16 + n16)*256 + q8;
      h8 A2[8];
      #pragma unroll
      for (int ks=0;ks<8;ks++) A2[ks] = *(const h8*)(Wb + ks*32);
      #pragma unroll
      for (int nt=0; nt<8; nt++){
        int node = nb + nt*16 + n16;
        bool ok = node < Nn;
        const _Float16* pp = phh + (size_t)(ok ? node : 0)*256 + q8;
        #pragma unroll
        for (int ks=0;ks<8;ks++){
          h8 bb = *(const h8*)(pp + ks*32);
          if (!ok) bb = zz;
          acc[ft][nt] = __builtin_amdgcn_mfma_f32_16x16x32_f16(A2[ks], bb, acc[ft][nt], 0,0,0);
        }
      }
    }
  }
  // stages that overwrite actL: wait for all waves' reads before writing
  if (S == 0 || S == 2) __syncthreads();
  #pragma unroll
  for (int ft=0;ft<2;ft++)
    #pragma unroll
    for (int nt=0;nt<8;nt++){
      int fb = w*32 + ft*16 + g*4;       // 4 consecutive features
      int nrow = nt*16 + n16;
      f4 a = acc[ft][nt];
      if (S == 0){
        h4 o;
        #pragma unroll
        for (int r=0;r<4;r++) o[r] = (_Float16)a[r];
        *(h4*)&actL[nrow*HSTRIDE + fb] = o;
      } else if (S == 1){
        h4 o;
        #pragma unroll
        for (int r=0;r<4;r++) o[r] = (_Float16)sigm1(a[r]);
        zr[ft*8+nt] = o;                  // z stays in registers (same wave owns frag in S3)
      } else if (S == 2){
        h4 hcv = *(const h4*)&actL[nrow*HSTRIDE + fb];
        h4 o;
        #pragma unroll
        for (int r=0;r<4;r++) o[r] = (_Float16)(sigm1(a[r]) * (float)hcv[r]);
        *(h4*)&actL[nrow*HSTRIDE + fb] = o;
      } else {
        h4 ho = *(const h4*)(h16 + (size_t)(nb+nrow)*128 + fb);
        h4 zv = zr[ft*8+nt];
        h4 o;
        #pragma unroll
        for (int r=0;r<4;r++){
          float z = (float)zv[r];
          o[r] = (_Float16)(z*(float)ho[r] + (1.f - z)*tanh1(a[r]));
        }
        *(h4*)(h16 + (size_t)(nb+nrow)*128 + fb) = o;
      }
    }
  if (S == 0 || S == 2) __syncthreads();
}

// __launch_bounds__(256,1): VGPR cap 512 -- the live set (~150 regs) must stay in
// registers. r10's (256,2) made the allocator cap at 128 and spill ~175 MB/dispatch
// to scratch (FETCH 95 MB / WRITE 143 MB). 2 waves/SIMD at ~170 VGPR = same 8
// waves/CU occupancy as r6, with 4x less L2 A-traffic.
__global__ __launch_bounds__(256, 1) void k_mainm(
    _Float16* __restrict__ h16, const void* __restrict__ x,
    const float* __restrict__ px1, const float* __restrict__ px2,
    const _Float16* __restrict__ phh,
    const _Float16* __restrict__ Wext, const _Float16* __restrict__ Whc,
    const int* __restrict__ flags, int t)
{
  __shared__ _Float16 actL[BLK_LDS];   // 44032 B
  int tid = threadIdx.x;
  int w = tid >> 6, lane = tid & 63;
  int nb = blockIdx.x*128;

  // ---- stage h16 -> actL[n][0..127]
  {
    int row = tid >> 1, c0 = (tid & 1)*64;
    const _Float16* hp = h16 + (size_t)(nb+row)*128 + c0;
    _Float16* dst = actL + row*HSTRIDE + c0;
    #pragma unroll
    for (int j=0;j<8;j++){
      h8 v = *(const h8*)(hp + j*8);
      h4* pv = (h4*)&v;
      *(h4*)(dst + j*8)     = pv[0];
      *(h4*)(dst + j*8 + 4) = pv[1];
    }
  }
  // ---- K-extension slots: actL[n][128..134] = {x0,x1,u1a,u1b,u2a,u2b,1}, 135..159 = 0
  if (tid < 128){
    int n = tid;
    _Float16* row = actL + n*HSTRIDE;
    for (int k=135;k<160;k++) row[k] = (_Float16)0.f;
    int isbf = flags[0];
    int i = nb + n;
    int b = i / Nn, nn2 = i - b*Nn;
    size_t xb = ((size_t)(b*Tt + t)*Nn + nn2)*2;
    float x0 = ldf(x,xb+0,isbf), x1 = ldf(x,xb+1,isbf);
    float u1a=0.f,u1b=0.f,u2a=-x0,u2b=-x1;   // nodes >= Nn: Tx1=0, Tx2=-x
    if (i < Nn){
      u1a = px1[(t*Nn+i)*2+0]; u1b = px1[(t*Nn+i)*2+1];
      u2a = 2.f*px2[(t*Nn+i)*2+0] - x0; u2b = 2.f*px2[(t*Nn+i)*2+1] - x1;
    }
    row[128]=(_Float16)x0;  row[129]=(_Float16)x1;
    row[130]=(_Float16)u1a; row[131]=(_Float16)u1b;
    row[132]=(_Float16)u2a; row[133]=(_Float16)u2b;
    row[134]=(_Float16)1.f;
  }
  __syncthreads();

  bool graphblk = (nb < Nn);   // block-uniform
  h4 zr[16];
  stage_mm<0>(Wext + 0*20480, Whc, phh, actL, zr, h16, nb, w, lane, graphblk);
  stage_mm<1>(Wext + 1*20480, Whc, phh, actL, zr, h16, nb, w, lane, graphblk);
  stage_mm<2>(Wext + 2*20480, Whc, phh, actL, zr, h16, nb, w, lane, graphblk);
  stage_mm<3>(Wext + 3*20480, Whc, phh, actL, zr, h16, nb, w, lane, graphblk);
}

// ---------------- output projection ----------------
__global__ __launch_bounds__(256) void k_out(
  const _Float16* __restrict__ h16, const void* __restrict__ Wo,
  const void* __restrict__ bo, void* __restrict__ out,
  const int* __restrict__ flags)
{
  __shared__ float wol[128*HORc];
  __shared__ float wob[HORc];
  int isbf = flags[0];
  for (int idx=threadIdx.x; idx<128*HORc; idx+=256) wol[idx] = ldf(Wo, idx, isbf);
  if (threadIdx.x < HORc) wob[threadIdx.x] = ldf(bo, threadIdx.x, isbf);
  __syncthreads();

  int i = blockIdx.x*256 + threadIdx.x;
  if (i < NTt){
    float acc[HORc];
    #pragma unroll
    for (int j=0;j<HORc;j++) acc[j] = wob[j];
    const _Float16* hp = h16 + (size_t)i*128;
    for (int kb=0;kb<16;kb++){
      h8 hv = *(const h8*)(hp + kb*8);
      #pragma unroll
      for (int j=0;j<8;j++){
        float hvf = (float)hv[j];
        #pragma unroll
        for (int jj=0;jj<HORc;jj++) acc[jj] += hvf * wol[(kb*8+j)*HORc + jj];
      }
    }
    int b = i / Nn, n = i - b*Nn;
    #pragma unroll
    for (int j=0;j<HORc;j++){
      size_t oi = (size_t)(b*HORc+j)*Nn + n;
      if (isbf) ((__hip_bfloat16*)out)[oi] = __float2bfloat16(acc[j]);
      else      ((float*)out)[oi] = acc[j];
    }
  }
}

// ---------------- host ----------------
extern "C" void kernel_launch(void* const* d_in, const int* in_sizes, int n_in,
                              void* d_out, int out_size, void* d_ws, size_t ws_size,
                              hipStream_t stream) {
  (void)in_sizes; (void)n_in; (void)out_size; (void)ws_size;
  const void* x   = d_in[0];
  const int*  edge= (const int*)d_in[1];
  const void* W1  = d_in[2];
  const void* b1  = d_in[3];
  const void* W2  = d_in[4];
  const void* b2  = d_in[5];
  const void* Wz  = d_in[6];
  const void* bz  = d_in[7];
  const void* Wr  = d_in[8];
  const void* br  = d_in[9];
  const void* Wc  = d_in[10];
  const void* bc  = d_in[11];
  const void* Wo  = d_in[12];
  const void* bo  = d_in[13];

  char* ws = (char*)d_ws;
  size_t off = 0;
  auto alloc = [&](size_t bytes)->char*{
    char* p = ws + off;
    off += (bytes + 255) & ~(size_t)255;
    return p;
  };
  _Float16* h16  = (_Float16*)alloc((size_t)NTt*128*2);   // 41 MB, zeroed
  int*   deg   = (int*)  alloc(Nn*4);                     // zeroed
  int*   cnt   = (int*)  alloc(Nn*4);                     // zeroed
  int*   fillc = (int*)  alloc(Nn*4);                     // zeroed
  size_t zlen = off;
  int*   flags = (int*)  alloc(16*4);
  float* dis   = (float*)alloc(Nn*4);
  int*   rowptr= (int*)  alloc((Nn+1)*4);
  int*   csr   = (int*)  alloc(Ee*4);
  float* px1   = (float*)alloc((size_t)Tt*Nn*2*4);
  float* px2   = (float*)alloc((size_t)Tt*Nn*2*4);
  _Float16* phh  = (_Float16*)alloc((size_t)5120*256*2);  // ph1|ph2 fp16 rows (padded)
  _Float16* Wext = (_Float16*)alloc((size_t)4*128*160*2);
  _Float16* Whc  = (_Float16*)alloc((size_t)128*256*2);

  hipMemsetAsync(d_ws, 0, zlen, stream);

  k_detect <<<1,256,0,stream>>>(W2, edge, flags);
  k_deg_cnt<<<(Ee+255)/256,256,0,stream>>>(edge, deg, cnt, flags);
  k_dis    <<<(Nn+255)/256,256,0,stream>>>(deg, dis);
  k_scan   <<<1,1024,0,stream>>>(cnt, rowptr);
  k_fill   <<<(Ee+255)/256,256,0,stream>>>(edge, rowptr, fillc, csr, flags);
  k_wx     <<<896,128,0,stream>>>(W1,b1,W2,b2,Wz,bz,Wr,br,Wc,bc, Wext, Whc, flags);
  k_px1    <<<(Tt*Nn+255)/256,256,0,stream>>>(x, dis, rowptr, csr, px1, flags);
  k_px2    <<<(Tt*Nn+255)/256,256,0,stream>>>(px1, dis, rowptr, csr, px2);

  for (int t=0; t<Tt; ++t){
    k_ph1  <<<Nn/4,256,0,stream>>>(h16, dis, rowptr, csr, phh);
    k_ph2  <<<Nn/4,256,0,stream>>>(dis, rowptr, csr, phh);
    k_mainm<<<NTt/128,256,0,stream>>>(h16, x, px1, px2, phh, Wext, Whc, flags, t);
  }

  k_out<<<(NTt+255)/256,256,0,stream>>>(h16, Wo, bo, d_out, flags);
}